// Round 14
// baseline (447.580 us; speedup 1.0000x reference)
//
#include <hip/hip_runtime.h>
#include <math.h>

#pragma clang fp contract(off)

typedef unsigned int u32;
typedef unsigned short u16;

#define N_NEUR 262144                 // 32*8192 neurons
#define TT     128                    // time steps
#define OB     ((size_t)N_NEUR * TT)  // floats in spike region of out
#define PB     128                    // persistent blocks (<= 256 CUs)
#define PT     256                    // threads/block (4 waves)
#define NW     4
#define NN     8                      // neurons per thread
#define NREP   16                     // count-array replicas (8 pollers each)
#define WGUARD 4096                   // tight bounded spin: never wedges

__device__ __forceinline__ float wredf(float v) {
#pragma unroll
  for (int o = 32; o; o >>= 1) v += __shfl_xor(v, o);
  return v;
}
__device__ __forceinline__ int wredi(int v) {
#pragma unroll
  for (int o = 32; o; o >>= 1) v += __shfl_xor(v, o);
  return v;
}

__launch_bounds__(PT)
__global__ void snn_persist(const float* __restrict__ in, const float* __restrict__ tsp,
                            const float* __restrict__ abp, float* __restrict__ out,
                            u32* __restrict__ bits2, u16* __restrict__ g_rep,
                            float* __restrict__ wm, float* __restrict__ wt,
                            float* __restrict__ wa)
{
#pragma clang fp contract(off)
  const int tid  = threadIdx.x;
  const int bid  = blockIdx.x;
  const int gtid = bid * PT + tid;          // 0..32767, 8 neurons each
  const int lane = tid & 63;
  const int wv   = tid >> 6;
  const int rep  = bid & (NREP - 1);

  // Verified-exact constants (R6-R13, spikes absmax 0.0): CR expf of f32 quotients.
  const float alp = __uint_as_float(0x3F7383C5u);
  const float bet = __uint_as_float(0x3F519856u);
  const float gma = __uint_as_float(0x3F7D73E8u);
  const float omg = 1.0f - gma;
  const float tsv = tsp[0];
  const float abv = abp[0];

  const int n0 = gtid * NN;
  const float4* q[NN];
#pragma unroll
  for (int j = 0; j < NN; ++j)
    q[j] = (const float4*)(in + (size_t)(n0 + j) * TT);

  float4 c[NN], f[NN];
#pragma unroll
  for (int j = 0; j < NN; ++j) { c[j] = q[j][0]; f[j] = q[j][1]; }

  // advance state from zeros to step 0 (byte-identical fma chain)
  float S[NN], Mp[NN], A[NN], M[NN];
#pragma unroll
  for (int j = 0; j < NN; ++j) {
    S[j]  = __builtin_fmaf(bet, 0.0f, c[j].x);
    Mp[j] = __builtin_fmaf(alp, 0.0f, S[j]);
    A[j]  = __builtin_fmaf(gma, 0.0f, omg * Mp[j]);
  }

  float ema = 0.0f;
  float sc  = (tsv + 0.1f * fmaxf(0.0f - 0.01f, 0.0f)) + abv;   // homeo(0)=0

  __shared__ int   shc[NW];
  __shared__ float shm[NW];
  __shared__ u32   s_tot;

  const u32* g32 = (const u32*)g_rep;   // poll view: 64 u32 per replica

  // One step, 2-leg sync (R13-verified mechanics, u16 slots):
  // decide -> wave+LDS count fold -> publish u16 to 16 replicas -> [compiler
  // barrier] -> hidden work (bits/traces/state advance) -> poll own replica
  // (ONE u32 load/lane) -> local exact integer sum -> ema/sc locally.
#define STEP(T_, INEXPR) {                                                     \
    u32 nib = 0; int cnt = 0;                                                  \
    _Pragma("unroll")                                                          \
    for (int j = 0; j < NN; ++j) {                                             \
      const float th_ = __builtin_fmaf(0.1f, A[j], sc);                        \
      const bool sp_ = (Mp[j] >= th_);                                         \
      M[j] = sp_ ? Mp[j] - th_ : Mp[j];                                        \
      cnt += (int)sp_;                                                         \
      nib |= ((u32)sp_) << j;                                                  \
    }                                                                          \
    cnt = wredi(cnt);                                                          \
    if (lane == 0) shc[wv] = cnt;                                              \
    __syncthreads();                                                           \
    if (tid < NREP) {                                                          \
      const int bc = ((shc[0] + shc[1]) + shc[2]) + shc[3];                    \
      __hip_atomic_store(&g_rep[((size_t)(T_) * NREP + tid) * PB + bid],       \
                         (u16)(bc + 1),                                        \
                         __ATOMIC_RELAXED, __HIP_MEMORY_SCOPE_AGENT);          \
    }                                                                          \
    asm volatile("" ::: "memory");  /* publish can never sink past the poll */ \
    /* ---- hidden under publish-visibility latency ---- */                    \
    u32 word = nib << (8 * (tid & 3));                                         \
    word |= (u32)__shfl_xor((int)word, 1);                                     \
    word |= (u32)__shfl_xor((int)word, 2);                                     \
    if ((tid & 3) == 0) bits2[(size_t)(gtid >> 2) * TT + (T_)] = word;         \
    float msum = 0.f, tsum = 0.f;                                              \
    _Pragma("unroll")                                                          \
    for (int j = 0; j < NN; ++j) {                                             \
      msum += M[j];                                                            \
      tsum += __builtin_fmaf(0.1f, A[j], sc);  /* recompute th, off-path */    \
    }                                                                          \
    msum = wredf(msum); tsum = wredf(tsum);                                    \
    if (lane == 0) {                                                           \
      wm[((size_t)(T_) * PB + bid) * NW + wv] = msum;                          \
      wt[((size_t)(T_) * PB + bid) * NW + wv] = tsum;                          \
    }                                                                          \
    if ((T_) < TT - 1) {   /* ema-independent advance to T_+1 */               \
      _Pragma("unroll")                                                        \
      for (int j = 0; j < NN; ++j) {                                           \
        const float I_ = (INEXPR);                                             \
        S[j]  = __builtin_fmaf(bet, S[j], I_);                                 \
        Mp[j] = __builtin_fmaf(alp, M[j], S[j]);                               \
        A[j]  = __builtin_fmaf(gma, A[j], omg * Mp[j]);                        \
      }                                                                        \
    }                                                                          \
    /* ---- detect: ONE u32 load/lane over own replica ---- */                 \
    if (wv == 0) {                                                             \
      const u32* pollp = g32 + ((size_t)(T_) * NREP + rep) * (PB / 2);         \
      u32 v_; int gd_ = 0;                                                     \
      while (1) {                                                              \
        v_ = __hip_atomic_load(&pollp[lane], __ATOMIC_RELAXED,                 \
                               __HIP_MEMORY_SCOPE_AGENT);                      \
        if (__all(((v_ & 0xFFFFu) != 0u) && ((v_ >> 16) != 0u))) break;        \
        if (++gd_ > WGUARD) break;                                             \
        if (gd_ > 64) __builtin_amdgcn_s_sleep(1);                             \
      }                                                                        \
      const u32 lo_ = v_ & 0xFFFFu, hi_ = v_ >> 16;                            \
      int ss_ = (int)(lo_ ? lo_ - 1u : 0u) + (int)(hi_ ? hi_ - 1u : 0u);       \
      ss_ = wredi(ss_);                                                        \
      if (lane == 0) s_tot = (u32)ss_;                                         \
    }                                                                          \
    __syncthreads();                                                           \
    const float mean_ = (float)s_tot * 3.814697265625e-06f;  /* *2^-18 */      \
    ema = __builtin_fmaf(0.99f, ema, 0.01f * mean_);                           \
    sc  = (tsv + 0.1f * fmaxf(ema - 0.01f, 0.0f)) + abv;                       \
  }

#pragma unroll 1
  for (int qq = 0; qq < 32; ++qq) {
    float4 p[NN];
#pragma unroll
    for (int j = 0; j < NN; ++j) p[j] = make_float4(0.f, 0.f, 0.f, 0.f);
    if (qq < 30) {
#pragma unroll
      for (int j = 0; j < NN; ++j) p[j] = q[j][qq + 2];
    }
    const int tb = 4 * qq;
    STEP(tb + 0, c[j].y)
    STEP(tb + 1, c[j].z)
    STEP(tb + 2, c[j].w)
    STEP(tb + 3, f[j].x)
#pragma unroll
    for (int j = 0; j < NN; ++j) { c[j] = f[j]; f[j] = p[j]; }
  }
#undef STEP

  // final adaptation partial; ema identical in every block
  float asum = 0.f;
#pragma unroll
  for (int j = 0; j < NN; ++j) asum += A[j];
  asum = wredf(asum);
  if (lane == 0) shm[wv] = asum;
  __syncthreads();
  if (tid == 0) {
    float bs = ((shm[0] + shm[1]) + shm[2]) + shm[3];
    wa[bid] = bs;
    if (bid == 0) out[OB + 256] = ema;   // ema after step 127
  }
}

// Deterministic fold of per-wave trace partials (512 per step, fixed order).
__launch_bounds__(256)
__global__ void snn_finish(const float* __restrict__ wm, const float* __restrict__ wt,
                           const float* __restrict__ wa, float* __restrict__ out)
{
#pragma clang fp contract(off)
  const int tid = threadIdx.x;
  const float inv = 3.814697265625e-06f;   // 2^-18
  if (tid < 128) {
    float s = 0.f;
    for (int j = 0; j < PB * NW; ++j) s += wm[(size_t)tid * PB * NW + j];
    out[OB + tid] = s * inv;
  } else {
    const int t = tid - 128;
    float s = 0.f;
    for (int j = 0; j < PB * NW; ++j) s += wt[(size_t)t * PB * NW + j];
    out[OB + 128 + t] = s * inv;
  }
  if (tid == 0) {
    float s = 0.f;
    for (int b = 0; b < PB; ++b) s += wa[b];
    out[OB + 257] = s * inv;
  }
}

// bits2[word][t] -> float spikes [n][t]; uint4 reads + float4 writes, coalesced.
__global__ void snn_expand(const u32* __restrict__ bits2, float* __restrict__ outF)
{
  const int gtid = blockIdx.x * blockDim.x + threadIdx.x;
  const int wave = gtid >> 6, lane = gtid & 63;
  const int nwaves = (gridDim.x * blockDim.x) >> 6;
  const int nloc = lane >> 5;     // which neuron of the pair
  const int tq   = lane & 31;     // float4 chunk over t
  for (int pair = wave; pair < N_NEUR / 2; pair += nwaves) {
    const int n = 2 * pair + nloc;
    const uint4 w = *(const uint4*)(bits2 + (size_t)(n >> 5) * TT + 4 * tq);
    const int b = n & 31;
    float4 f;
    f.x = (float)((w.x >> b) & 1u);
    f.y = (float)((w.y >> b) & 1u);
    f.z = (float)((w.z >> b) & 1u);
    f.w = (float)((w.w >> b) & 1u);
    ((float4*)outF)[(size_t)n * (TT / 4) + tq] = f;
  }
}

extern "C" void kernel_launch(void* const* d_in, const int* in_sizes, int n_in,
                              void* d_out, int out_size, void* d_ws, size_t ws_size,
                              hipStream_t stream)
{
  const float* in  = (const float*)d_in[0];
  const float* tsp = (const float*)d_in[1];
  const float* abp = (const float*)d_in[2];
  float* out = (float*)d_out;
  unsigned char* ws = (unsigned char*)d_ws;

  if (ws_size < 5243392u) return;   // need exactly 5243392 B of scratch

  u32* bits2 = (u32*)(ws);                      // 4 MiB   [8192 words][128 t]
  u16* g_rep = (u16*)(ws + 4194304);            // 512 KiB [128 t][16 rep][128 u16]
  float* wm  = (float*)(ws + 4718592);          // 256 KiB [128 t][128 b][4 w]  -> ends 4980736
  float* wt  = (float*)(ws + 4980736);          // 256 KiB                      -> ends 5242880
  float* wa  = (float*)(ws + 5242880);          // 512 B  (FIX: was inside wt)

  hipMemsetAsync(g_rep, 0, 524288, stream);     // zero replica slots (in-graph)

  snn_persist<<<dim3(PB), dim3(PT), 0, stream>>>(in, tsp, abp, out,
                                                 bits2, g_rep, wm, wt, wa);
  snn_finish<<<dim3(1), dim3(256), 0, stream>>>(wm, wt, wa, out);
  snn_expand<<<dim3(2048), dim3(256), 0, stream>>>(bits2, out);
}

// Round 16
// 367.367 us; speedup vs baseline: 1.2183x; 1.2183x over previous
//
#include <hip/hip_runtime.h>
#include <math.h>

#pragma clang fp contract(off)

typedef unsigned int u32;

#define N_NEUR 262144                 // 32*8192 neurons
#define TT     128                    // time steps
#define OB     ((size_t)N_NEUR * TT)  // floats in spike region of out
#define PB     128                    // persistent blocks (<= 256 CUs -> co-resident)
#define PT     512                    // threads/block (8 waves)
#define NW     8
#define NREP   16                     // count-array replicas (8 poller blocks each)
#define WGUARD (1 << 17)              // bounded spin: terminate, never hang

__device__ __forceinline__ float wredf(float v) {
#pragma unroll
  for (int o = 32; o; o >>= 1) v += __shfl_xor(v, o);
  return v;
}
__device__ __forceinline__ int wredi(int v) {
#pragma unroll
  for (int o = 32; o; o >>= 1) v += __shfl_xor(v, o);
  return v;
}

// ===== snn_persist: BYTE-IDENTICAL to the R11 kernel that passed at 342 us =====
__launch_bounds__(PT)
__global__ void snn_persist(const float* __restrict__ in, const float* __restrict__ tsp,
                            const float* __restrict__ abp, float* __restrict__ out,
                            u32* __restrict__ bits2, u32* __restrict__ g_rep,
                            float* __restrict__ wm, float* __restrict__ wt,
                            float* __restrict__ wa)
{
#pragma clang fp contract(off)
  const int tid  = threadIdx.x;
  const int bid  = blockIdx.x;
  const int gtid = bid * PT + tid;          // 0..65535, 4 neurons each
  const int lane = tid & 63;
  const int wv   = tid >> 6;
  const int rep  = bid & (NREP - 1);        // which replica this block polls

  // Verified-exact constants (R6-R14, absmax 0.0): CR expf of f32 quotients.
  const float alp = __uint_as_float(0x3F7383C5u);
  const float bet = __uint_as_float(0x3F519856u);
  const float gma = __uint_as_float(0x3F7D73E8u);
  const float omg = 1.0f - gma;
  const float tsv = tsp[0];
  const float abv = abp[0];

  const int n0 = gtid * 4;
  const float4* q0 = (const float4*)(in + (size_t)(n0 + 0) * TT);
  const float4* q1 = (const float4*)(in + (size_t)(n0 + 1) * TT);
  const float4* q2 = (const float4*)(in + (size_t)(n0 + 2) * TT);
  const float4* q3 = (const float4*)(in + (size_t)(n0 + 3) * TT);

  float4 c0 = q0[0], c1 = q1[0], c2 = q2[0], c3 = q3[0];   // chunk q   (steps 4q..4q+3)
  float4 f0 = q0[1], f1 = q1[1], f2 = q2[1], f3 = q3[1];   // chunk q+1

  // advance state from zeros to step 0 (byte-identical fma chain)
  float S0,S1,S2,S3, Mp0,Mp1,Mp2,Mp3, A0,A1,A2,A3;
  S0 = __builtin_fmaf(bet, 0.0f, c0.x); Mp0 = __builtin_fmaf(alp, 0.0f, S0);
  A0 = __builtin_fmaf(gma, 0.0f, omg * Mp0);
  S1 = __builtin_fmaf(bet, 0.0f, c1.x); Mp1 = __builtin_fmaf(alp, 0.0f, S1);
  A1 = __builtin_fmaf(gma, 0.0f, omg * Mp1);
  S2 = __builtin_fmaf(bet, 0.0f, c2.x); Mp2 = __builtin_fmaf(alp, 0.0f, S2);
  A2 = __builtin_fmaf(gma, 0.0f, omg * Mp2);
  S3 = __builtin_fmaf(bet, 0.0f, c3.x); Mp3 = __builtin_fmaf(alp, 0.0f, S3);
  A3 = __builtin_fmaf(gma, 0.0f, omg * Mp3);

  float ema = 0.0f;
  float sc  = (tsv + 0.1f * fmaxf(0.0f - 0.01f, 0.0f)) + abv;   // homeo(ema=0)=0

  __shared__ int   shc[NW];
  __shared__ float shm[NW];
  __shared__ u32   s_tot;

  float M0, M1, M2, M3;   // post-reset membranes of the current step

  // One step, 2-leg sync: spike decide -> block count reduce -> publish to all
  // 16 replicas (one store, lanes 0-15) -> [hidden: bits/traces/state advance]
  // -> poll OWN replica all-nonzero -> local integer sum -> ema/sc locally.
#define STEP(T_, IN0, IN1, IN2, IN3) {                                         \
    const float th0 = __builtin_fmaf(0.1f, A0, sc);                            \
    const float th1 = __builtin_fmaf(0.1f, A1, sc);                            \
    const float th2 = __builtin_fmaf(0.1f, A2, sc);                            \
    const float th3 = __builtin_fmaf(0.1f, A3, sc);                            \
    const bool sp0 = (Mp0 >= th0);  M0 = sp0 ? Mp0 - th0 : Mp0;                \
    const bool sp1 = (Mp1 >= th1);  M1 = sp1 ? Mp1 - th1 : Mp1;                \
    const bool sp2 = (Mp2 >= th2);  M2 = sp2 ? Mp2 - th2 : Mp2;                \
    const bool sp3 = (Mp3 >= th3);  M3 = sp3 ? Mp3 - th3 : Mp3;                \
    int cnt = (int)sp0 + (int)sp1 + (int)sp2 + (int)sp3;                       \
    cnt = wredi(cnt);                                                          \
    if (lane == 0) shc[wv] = cnt;                                              \
    __syncthreads();                                                           \
    if (tid < NREP) {  /* each lane publishes to one replica: 1 instruction */ \
      const int bc = ((((((shc[0] + shc[1]) + shc[2]) + shc[3]) + shc[4])      \
                       + shc[5]) + shc[6]) + shc[7];                           \
      __hip_atomic_store(&g_rep[((size_t)(T_) * NREP + tid) * PB + bid],       \
                         (u32)bc + 1u,                                         \
                         __ATOMIC_RELAXED, __HIP_MEMORY_SCOPE_AGENT);          \
    }                                                                          \
    /* ---- hidden under publish-visibility latency ---- */                    \
    u32 nib = (u32)sp0 | ((u32)sp1 << 1) | ((u32)sp2 << 2) | ((u32)sp3 << 3);  \
    u32 word = nib << (4 * (tid & 7));                                         \
    word |= (u32)__shfl_xor((int)word, 1);                                     \
    word |= (u32)__shfl_xor((int)word, 2);                                     \
    word |= (u32)__shfl_xor((int)word, 4);                                     \
    if ((tid & 7) == 0) bits2[(size_t)(gtid >> 3) * TT + (T_)] = word;         \
    float msum = ((M0 + M1) + M2) + M3;                                        \
    float tsum = ((th0 + th1) + th2) + th3;                                    \
    msum = wredf(msum); tsum = wredf(tsum);                                    \
    if (lane == 0) {                                                           \
      wm[((size_t)(T_) * PB + bid) * NW + wv] = msum;                          \
      wt[((size_t)(T_) * PB + bid) * NW + wv] = tsum;                          \
    }                                                                          \
    if ((T_) < TT - 1) {  /* ema-independent advance to step T_+1 */           \
      S0 = __builtin_fmaf(bet, S0, (IN0));                                     \
      Mp0 = __builtin_fmaf(alp, M0, S0);                                       \
      A0 = __builtin_fmaf(gma, A0, omg * Mp0);                                 \
      S1 = __builtin_fmaf(bet, S1, (IN1));                                     \
      Mp1 = __builtin_fmaf(alp, M1, S1);                                       \
      A1 = __builtin_fmaf(gma, A1, omg * Mp1);                                 \
      S2 = __builtin_fmaf(bet, S2, (IN2));                                     \
      Mp2 = __builtin_fmaf(alp, M2, S2);                                       \
      A2 = __builtin_fmaf(gma, A2, omg * Mp2);                                 \
      S3 = __builtin_fmaf(bet, S3, (IN3));                                     \
      Mp3 = __builtin_fmaf(alp, M3, S3);                                       \
      A3 = __builtin_fmaf(gma, A3, omg * Mp3);                                 \
    }                                                                          \
    /* ---- detect on own replica + local exact sum ---- */                    \
    if (wv == 0) {                                                             \
      const u32* slots_ = g_rep + ((size_t)(T_) * NREP + rep) * PB;            \
      u32 v0_, v1_; int gd_ = 0;                                               \
      while (1) {                                                              \
        v0_ = __hip_atomic_load(&slots_[lane],      __ATOMIC_RELAXED,          \
                                __HIP_MEMORY_SCOPE_AGENT);                     \
        v1_ = __hip_atomic_load(&slots_[lane + 64], __ATOMIC_RELAXED,          \
                                __HIP_MEMORY_SCOPE_AGENT);                     \
        if (__all(v0_ != 0u && v1_ != 0u)) break;                              \
        if (++gd_ > WGUARD) break;                                             \
      }                                                                        \
      int ss_ = (int)(v0_ ? v0_ - 1u : 0u) + (int)(v1_ ? v1_ - 1u : 0u);       \
      ss_ = wredi(ss_);                                                        \
      if (lane == 0) s_tot = (u32)ss_;                                         \
    }                                                                          \
    __syncthreads();                                                           \
    const float mean_ = (float)s_tot * 3.814697265625e-06f;  /* *2^-18 */      \
    ema = __builtin_fmaf(0.99f, ema, 0.01f * mean_);                           \
    sc  = (tsv + 0.1f * fmaxf(ema - 0.01f, 0.0f)) + abv;                       \
  }

#pragma unroll 1
  for (int q = 0; q < 32; ++q) {
    float4 p0 = {0,0,0,0}, p1 = {0,0,0,0}, p2 = {0,0,0,0}, p3 = {0,0,0,0};
    if (q < 30) { p0 = q0[q + 2]; p1 = q1[q + 2]; p2 = q2[q + 2]; p3 = q3[q + 2]; }
    const int tb = 4 * q;
    STEP(tb + 0, c0.y, c1.y, c2.y, c3.y)
    STEP(tb + 1, c0.z, c1.z, c2.z, c3.z)
    STEP(tb + 2, c0.w, c1.w, c2.w, c3.w)
    STEP(tb + 3, f0.x, f1.x, f2.x, f3.x)
    c0 = f0; c1 = f1; c2 = f2; c3 = f3;
    f0 = p0; f1 = p1; f2 = p2; f3 = p3;
  }
#undef STEP

  // final adaptation partial: A holds a(127); final ema identical everywhere
  float asum = ((A0 + A1) + A2) + A3;
  asum = wredf(asum);
  if (lane == 0) shm[wv] = asum;
  __syncthreads();
  if (tid == 0) {
    float bs = 0.f;
    for (int w = 0; w < NW; ++w) bs += shm[w];
    wa[bid] = bs;
    if (bid == 0) out[OB + 256] = ema;   // ema after step 127 (exact, local)
  }
}

// Merged tail (sync-free, trivially terminating): block 0 folds trace partials
// in deterministic order into out[OB..OB+257]; ALL blocks expand bits2 ->
// float spikes into out[0..OB).  Regions disjoint; inputs read-only.
__launch_bounds__(256)
__global__ void snn_tail(const u32* __restrict__ bits2, const float* __restrict__ wm,
                         const float* __restrict__ wt, const float* __restrict__ wa,
                         float* __restrict__ out)
{
#pragma clang fp contract(off)
  const int tid = threadIdx.x;
  if (blockIdx.x == 0) {
    const float inv = 3.814697265625e-06f;   // 2^-18
    if (tid < 128) {
      float s = 0.f;
      for (int j = 0; j < PB * NW; ++j) s += wm[(size_t)tid * PB * NW + j];
      out[OB + tid] = s * inv;
    } else {
      const int t = tid - 128;
      float s = 0.f;
      for (int j = 0; j < PB * NW; ++j) s += wt[(size_t)t * PB * NW + j];
      out[OB + 128 + t] = s * inv;
    }
    if (tid == 0) {
      float s = 0.f;
      for (int b = 0; b < PB; ++b) s += wa[b];
      out[OB + 257] = s * inv;
    }
  }
  // expand: uint4 reads + float4 writes, fully coalesced, grid-stride
  const int gtid = blockIdx.x * blockDim.x + tid;
  const int wave = gtid >> 6, lane = gtid & 63;
  const int nwaves = (gridDim.x * blockDim.x) >> 6;
  const int nloc = lane >> 5;     // which neuron of the pair
  const int tq   = lane & 31;     // float4 chunk over t
  for (int pair = wave; pair < N_NEUR / 2; pair += nwaves) {
    const int n = 2 * pair + nloc;
    const uint4 w = *(const uint4*)(bits2 + (size_t)(n >> 5) * TT + 4 * tq);
    const int b = n & 31;
    float4 f;
    f.x = (float)((w.x >> b) & 1u);
    f.y = (float)((w.y >> b) & 1u);
    f.z = (float)((w.z >> b) & 1u);
    f.w = (float)((w.w >> b) & 1u);
    ((float4*)out)[(size_t)n * (TT / 4) + tq] = f;
  }
}

extern "C" void kernel_launch(void* const* d_in, const int* in_sizes, int n_in,
                              void* d_out, int out_size, void* d_ws, size_t ws_size,
                              hipStream_t stream)
{
  const float* in  = (const float*)d_in[0];
  const float* tsp = (const float*)d_in[1];
  const float* abp = (const float*)d_in[2];
  float* out = (float*)d_out;
  unsigned char* ws = (unsigned char*)d_ws;

  if (ws_size < 6292000u) return;   // need ~6.0 MiB scratch

  u32*   bits2 = (u32*)(ws);                    // 4 MiB   [8192 words][128 t]
  float* wm    = (float*)(ws + 4194304);        // 512 KiB [128 t][128 b][8 w]
  float* wt    = (float*)(ws + 4718592);        // 512 KiB -> ends 5242880
  u32*   g_rep = (u32*)(ws + 5242880);          // 1 MiB   [128 t][16 rep][128 slot]
  float* wa    = (float*)(ws + 6291456);        // 512 B   (after g_rep)

  hipMemsetAsync(g_rep, 0, 1048576, stream);    // zero replica slots (in-graph)

  snn_persist<<<dim3(PB), dim3(PT), 0, stream>>>(in, tsp, abp, out,
                                                 bits2, g_rep, wm, wt, wa);
  snn_tail<<<dim3(2048), dim3(256), 0, stream>>>(bits2, wm, wt, wa, out);
}